// Round 3
// baseline (1024.577 us; speedup 1.0000x reference)
//
#include <hip/hip_runtime.h>
#include <math.h>

// Problem constants (from reference): B=2, N=4096, E=16384, D=64, OUT=64
#define BB 2
#define NN 4096      // 2^12
#define EE 16384     // 2^14
#define DD 64
#define OO 64
// flat element index in [B,N,E]: fe = b*(N*E) + n*E + e ; N*E = 2^26, E = 2^14

// clang native vector type (16 B loads)
typedef unsigned int v4u __attribute__((ext_vector_type(4)));

// ---------------------------------------------------------------------------
// Kernel 1: recover ri_idx/ro_idx from the one-hot incidence matrices.
// R5 unit-stride streaming (kept; R3/R5 stride variants measured equal).
// R7 change: zeroes the 16K-int CSR histogram instead of mi/mo — the CSR
// gather kernel now overwrites mi/mo unconditionally, so no pre-zero needed.
// Must scan all 1.073 GB of Ri+Ro: HBM floor ~170 us at fill-proven 6.4 TB/s.
// ---------------------------------------------------------------------------
__global__ __launch_bounds__(256) void extract_idx_kernel(
    const v4u* __restrict__ Ri, const v4u* __restrict__ Ro,
    int* __restrict__ ri_idx, int* __restrict__ ro_idx,
    int* __restrict__ cnt)    // [2*BB*NN] = 16384 ints, zeroed here
{
    unsigned gid = blockIdx.x * blockDim.x + threadIdx.x;  // 0 .. 2^21-1
    const unsigned HALF = 1u << 20;                        // threads per matrix

    if (gid < 2u * BB * NN) cnt[gid] = 0;   // stream-ordered: hist runs after

    const v4u* __restrict__ src = (gid < HALF) ? Ri : Ro;
    int* __restrict__ idx       = (gid < HALF) ? ri_idx : ro_idx;
    unsigned lgid = gid & (HALF - 1);

    // 2^25 v4u per matrix / 2^20 threads = 32 iterations, unit lane stride.
    #pragma unroll 4
    for (unsigned k = 0; k < 32; ++k) {
        unsigned i = lgid + k * HALF;
        v4u a = src[i];
        if (a.x | a.y | a.z | a.w) {         // rare (p ~ 1/1024 per lane)
            unsigned fe = i * 4u;            // flat element index in [B,N,E]
            int e = (int)(fe & (EE - 1));    // 4 consecutive e's, same (b,n)
            int n = (int)((fe >> 14) & (NN - 1));
            int b = (int)(fe >> 26);
            int base = b * EE + e;
            if (a.x) idx[base + 0] = n;
            if (a.y) idx[base + 1] = n;
            if (a.z) idx[base + 2] = n;
            if (a.w) idx[base + 3] = n;
        }
    }
}

// ---------------------------------------------------------------------------
// Kernel 2 (new, R7): per-node degree histogram for both directions.
// seg = dir*BB + b ; dir 0 bins by ri (feeds mi), dir 1 bins by ro (feeds mo).
// 65K int atomics on a 64 KB counter array — microseconds.
// ---------------------------------------------------------------------------
__global__ __launch_bounds__(256) void hist_kernel(
    const int* __restrict__ ri_idx, const int* __restrict__ ro_idx,
    int* __restrict__ cnt)
{
    int t = blockIdx.x * blockDim.x + threadIdx.x;   // 0 .. BB*EE-1
    if (t >= BB * EE) return;
    int b = t >> 14;
    atomicAdd(&cnt[(0 * BB + b) * NN + ri_idx[t]], 1);
    atomicAdd(&cnt[(1 * BB + b) * NN + ro_idx[t]], 1);
}

// ---------------------------------------------------------------------------
// Kernel 3 (new, R7): exclusive prefix sum over each segment's 4096 bins.
// 4 blocks (one per seg), 1024 threads, Hillis-Steele in LDS.
// Writes start_ (preserved for gather) and cursor (consumed by place).
// ---------------------------------------------------------------------------
__global__ __launch_bounds__(1024) void scan_kernel(
    const int* __restrict__ cnt, int* __restrict__ start_,
    int* __restrict__ cursor)
{
    int seg = blockIdx.x;                  // 0..3
    const int* c = cnt + seg * NN;
    int tid = threadIdx.x;                 // 0..1023, owns bins 4t..4t+3
    int v0 = c[tid * 4 + 0], v1 = c[tid * 4 + 1];
    int v2 = c[tid * 4 + 2], v3 = c[tid * 4 + 3];
    int tsum = v0 + v1 + v2 + v3;

    __shared__ int lds[1024];
    lds[tid] = tsum;
    __syncthreads();
    for (int off = 1; off < 1024; off <<= 1) {
        int x = (tid >= off) ? lds[tid - off] : 0;
        __syncthreads();
        lds[tid] += x;
        __syncthreads();
    }
    int excl = lds[tid] - tsum;            // exclusive prefix of this group

    int s0 = excl, s1 = excl + v0, s2 = s1 + v1, s3 = s2 + v2;
    int* st = start_ + seg * NN;
    int* cu = cursor + seg * NN;
    st[tid * 4 + 0] = s0;  cu[tid * 4 + 0] = s0;
    st[tid * 4 + 1] = s1;  cu[tid * 4 + 1] = s1;
    st[tid * 4 + 2] = s2;  cu[tid * 4 + 2] = s2;
    st[tid * 4 + 3] = s3;  cu[tid * 4 + 3] = s3;
}

// ---------------------------------------------------------------------------
// Kernel 4 (new, R7): place each edge into its per-node bucket (counting
// sort). For mi (dir 0, keyed by ri) store the SOURCE node ro and weight;
// for mo (dir 1, keyed by ro) store ri and weight. Positions claimed via
// atomicAdd on cursor — 65K int atomics, bijective within each segment.
// ---------------------------------------------------------------------------
__global__ __launch_bounds__(256) void place_kernel(
    const int* __restrict__ ri_idx, const int* __restrict__ ro_idx,
    const float* __restrict__ ew, int* __restrict__ cursor,
    int* __restrict__ sro, float* __restrict__ swi,
    int* __restrict__ sri, float* __restrict__ swo)
{
    int t = blockIdx.x * blockDim.x + threadIdx.x;   // 0 .. BB*EE-1
    if (t >= BB * EE) return;
    int b = t >> 14;
    int ri = ri_idx[t], ro = ro_idx[t];
    float w = ew[t];
    int p0 = atomicAdd(&cursor[(0 * BB + b) * NN + ri], 1);
    sro[b * EE + p0] = ro;
    swi[b * EE + p0] = w;
    int p1 = atomicAdd(&cursor[(1 * BB + b) * NN + ro], 1);
    sri[b * EE + p1] = ri;
    swo[b * EE + p1] = w;
}

// ---------------------------------------------------------------------------
// Kernel 5 (R7, replaces atomic scatter): one wave per (dir, b, n).
// Register-accumulate the node's ~4 edges (Poisson(4), max ~18) from the
// sorted bucket, then ONE plain 256 B store. Zero atomics on mi/mo, no
// pre-zero. X gathers are 256 B coalesced, L2-resident (X = 2 MB).
// ---------------------------------------------------------------------------
__global__ __launch_bounds__(256) void gather_kernel(
    const float* __restrict__ X,
    const int* __restrict__ start_, const int* __restrict__ cnt,
    const int* __restrict__ sro, const float* __restrict__ swi,
    const int* __restrict__ sri, const float* __restrict__ swo,
    float* __restrict__ mi, float* __restrict__ mo)
{
    int wid = (blockIdx.x * blockDim.x + threadIdx.x) >> 6;  // 0 .. 2*BB*NN-1
    int lane = threadIdx.x & 63;
    if (wid >= 2 * BB * NN) return;
    int dir = wid >> 13;               // BB*NN = 2^13
    int rem = wid & (BB * NN - 1);
    int b = rem >> 12;                 // NN = 2^12
    int n = rem & (NN - 1);
    int seg = dir * BB + b;

    int s = __builtin_amdgcn_readfirstlane(start_[seg * NN + n]);
    int c = __builtin_amdgcn_readfirstlane(cnt[seg * NN + n]);

    const int*   sidx = dir ? sri : sro;
    const float* sw   = dir ? swo : swi;
    const float* xb = X + (size_t)b * NN * DD;

    float acc = 0.0f;
    for (int k = s; k < s + c; ++k) {
        int src = sidx[b * EE + k];    // wave-uniform -> broadcast load
        float w = sw[b * EE + k];
        acc += w * xb[src * DD + lane];
    }
    float* dst = dir ? mo : mi;
    dst[(size_t)(b * NN + n) * DD + lane] = acc;
}

// ---------------------------------------------------------------------------
// Kernel 6: per-node MLP, one WAVE per node, lane j = output channel
// (unchanged — L1-hot weights, full occupancy).
// ---------------------------------------------------------------------------
__global__ __launch_bounds__(256) void mlp_kernel(
    const float* __restrict__ X, const float* __restrict__ mi,
    const float* __restrict__ mo,
    const float* __restrict__ W1, const float* __restrict__ b1,
    const float* __restrict__ W2, const float* __restrict__ b2,
    float* __restrict__ out)
{
    int wid = (blockIdx.x * blockDim.x + threadIdx.x) >> 6;   // node id
    int lane = threadIdx.x & 63;
    if (wid >= BB * NN) return;

    float acc = b1[lane];
    const float* srcs[3];
    srcs[0] = mi + (size_t)wid * DD;
    srcs[1] = mo + (size_t)wid * DD;
    srcs[2] = X  + (size_t)wid * DD;

    for (int part = 0; part < 3; ++part) {
        float fv = srcs[part][lane];          // lane k holds feat[k]
        const float* wbase = W1 + (size_t)part * DD * OO;
        #pragma unroll
        for (int k = 0; k < DD; ++k) {
            float fk = __shfl(fv, k, 64);
            acc += fk * wbase[k * OO + lane]; // coalesced row, L1-hot
        }
    }
    float h = tanhf(acc);

    float acc2 = b2[lane];
    #pragma unroll
    for (int k = 0; k < OO; ++k) {
        float hk = __shfl(h, k, 64);
        acc2 += hk * W2[k * OO + lane];
    }
    out[(size_t)wid * OO + lane] = tanhf(acc2);
}

// ---------------------------------------------------------------------------
extern "C" void kernel_launch(void* const* d_in, const int* in_sizes, int n_in,
                              void* d_out, int out_size, void* d_ws, size_t ws_size,
                              hipStream_t stream)
{
    const float* X  = (const float*)d_in[0];   // [B,N,D]
    const float* ew = (const float*)d_in[1];   // [B,E]
    const float* Ri = (const float*)d_in[2];   // [B,N,E]
    const float* Ro = (const float*)d_in[3];   // [B,N,E]
    const float* W1 = (const float*)d_in[4];   // [3D,OUT]
    const float* b1 = (const float*)d_in[5];   // [OUT]
    const float* W2 = (const float*)d_in[6];   // [OUT,OUT]
    const float* b2 = (const float*)d_in[7];   // [OUT]
    float* out = (float*)d_out;                // [B,N,OUT]

    // workspace layout (ws re-poisoned each call -> every buffer below is
    // fully re-initialized every call; audit in each kernel's comment)
    float* mi     = (float*)d_ws;                        // 2 MB
    float* mo     = mi + (size_t)BB * NN * DD;           // 2 MB
    int*   ri_idx = (int*)(mo + (size_t)BB * NN * DD);   // 128 KB
    int*   ro_idx = ri_idx + BB * EE;                    // 128 KB
    int*   cnt    = ro_idx + BB * EE;                    // 64 KB  [2*BB*NN]
    int*   start_ = cnt    + 2 * BB * NN;                // 64 KB
    int*   cursor = start_ + 2 * BB * NN;                // 64 KB
    int*   sro    = cursor + 2 * BB * NN;                // 128 KB
    int*   sri    = sro + BB * EE;                       // 128 KB
    float* swi    = (float*)(sri + BB * EE);             // 128 KB
    float* swo    = swi + BB * EE;                       // 128 KB

    extract_idx_kernel<<<8192, 256, 0, stream>>>(
        (const v4u*)Ri, (const v4u*)Ro, ri_idx, ro_idx, cnt);

    hist_kernel<<<(BB * EE) / 256, 256, 0, stream>>>(ri_idx, ro_idx, cnt);

    scan_kernel<<<4, 1024, 0, stream>>>(cnt, start_, cursor);

    place_kernel<<<(BB * EE) / 256, 256, 0, stream>>>(
        ri_idx, ro_idx, ew, cursor, sro, swi, sri, swo);

    gather_kernel<<<(2 * BB * NN * 64) / 256, 256, 0, stream>>>(
        X, start_, cnt, sro, swi, sri, swo, mi, mo);

    mlp_kernel<<<(BB * NN * 64) / 256, 256, 0, stream>>>(
        X, mi, mo, W1, b1, W2, b2, out);
}